// Round 8
// baseline (65.396 us; speedup 1.0000x reference)
//
#include <hip/hip_runtime.h>
#include <math.h>

#define L 4096
#define C2 32
#define CTOT 64
#define BB 4
#define NG 4
#define NSAMP 2048
#define SETSZ 256                 // samples per staged set (24 KB)
#define NSETS (NSAMP / SETSZ)     // 8
#define TPS (SETSZ / 32)          // 8 sample-tiles per set
#define TPB 128                   // 2 waves/block
#define RB 2                      // 32-row tiles per wave
#define ROWSPB 128                // (TPB/64)*RB*32

typedef _Float16 half8 __attribute__((ext_vector_type(8)));
typedef float f32x16 __attribute__((ext_vector_type(16)));

__device__ __forceinline__ void split3(float x, _Float16& h, _Float16& m, _Float16& l) {
    h = (_Float16)x;
    float r1 = x - (float)h;
    m = (_Float16)r1;
    float r2 = r1 - (float)m;
    l = (_Float16)r2;
}

// score[r,n] = sum_g ca*s^2 + cb*s (rc dropped, -nlp folded — argmax-invariant,
// established R2..R7 with absmax 0). fp32 via 3-way f16 split, 6 terms on
// v_mfma_f32_32x32x16_f16 (K=16 = [8 ca | 8 cb] exactly):
//   AhBh + AhBm + AmBh + AmBm + AhBl + AlBh   (dropped terms ~2^-33)
// A-frag: lane holds A[row=lane&31][k=(lane>>5)*8+j] (pattern validated at
// 16x16x32 in R7). D: col=lane&31, row=(reg&3)+8*(reg>>2)+4*(lane>>5) (m101).
// LDS per 32-sample tile: 3 levels x [kh=2][col=32] x 8 f16 = 3 KB; one b128
// per level per wave serves 2 row-tiles (RB=2) = 2048 entries.
__global__ __launch_bounds__(TPB) void gqreg_kernel(
    const float* __restrict__ z, const float* __restrict__ prior,
    float* __restrict__ out /* zhat [B][C2][L] then indices-as-float [B][NG][L] */)
{
    __shared__ _Float16 smem[TPS * 1536];   // 24 KB staging
    __shared__ int ebuf[TPB / 64][2][16];   // epilogue bounce: [wave][kh][reg]

    const int tid = threadIdx.x;
    const int lane = tid & 63;
    const int w = tid >> 6;
    const int col = lane & 31;
    const int kh = lane >> 5;
    char* sb = (char*)smem;
    const float4* p4 = (const float4*)prior;

    // ---- prefetch set 0 into registers (T14: issue early) ----
    float4 pf0, pf1, pf2, pf3;
    {
        int n0 = tid, n1 = tid + TPB;
        pf0 = p4[2 * n0]; pf1 = p4[2 * n0 + 1];
        pf2 = p4[2 * n1]; pf3 = p4[2 * n1 + 1];
    }

    // ---- A-side coefficients: lane(row=col, kh) holds k=kh*8+g ----
    const int rowbase = blockIdx.x * ROWSPB + w * (RB * 32);
    half8 ah[RB], am[RB], al[RB];
    #pragma unroll
    for (int rb = 0; rb < RB; ++rb) {
        int r = rowbase + rb * 32 + col;
        int b = r >> 14, pos = (r >> 2) & (L - 1), ns = r & 3;
        const float* zb = z + (size_t)b * CTOT * L + pos;
        #pragma unroll
        for (int g = 0; g < 8; ++g) {
            float mu = zb[(size_t)(g * NG + ns) * L];
            float lv = zb[(size_t)(C2 + g * NG + ns) * L];
            lv = fminf(fmaxf(lv, -30.f), 20.f);
            float iv = expf(-lv);
            float x = kh ? (mu * iv) : (0.5f - 0.5f * iv);
            _Float16 xh, xm, xl;
            split3(x, xh, xm, xl);
            ah[rb][g] = xh; am[rb][g] = xm; al[rb][g] = xl;
        }
    }

    const int lofs = kh * 512 + col * 16;   // B-frag byte offset within a level

    float best[RB][16];
    int bidx[RB][16];
    #pragma unroll
    for (int rb = 0; rb < RB; ++rb)
        #pragma unroll
        for (int j = 0; j < 16; ++j) { best[rb][j] = -INFINITY; bidx[rb][j] = 0; }

    const f32x16 z16 = {};

    for (int set = 0; set < NSETS; ++set) {
        // ---- split current prefetch into LDS (2 samples/thread) ----
        #pragma unroll
        for (int ss = 0; ss < 2; ++ss) {
            int nl = tid + ss * TPB;
            float4 u = ss ? pf2 : pf0;
            float4 v = ss ? pf3 : pf1;
            float s[8] = {u.x, u.y, u.z, u.w, v.x, v.y, v.z, v.w};
            half8 qh, qm, ql, vh, vm, vl;
            #pragma unroll
            for (int g = 0; g < 8; ++g) {
                _Float16 hh, mm, ll;
                split3(s[g] * s[g], hh, mm, ll);
                qh[g] = hh; qm[g] = mm; ql[g] = ll;
                split3(s[g], hh, mm, ll);
                vh[g] = hh; vm[g] = mm; vl[g] = ll;
            }
            char* tb = sb + (nl >> 5) * 3072 + (nl & 31) * 16;
            *(half8*)(tb + 0)    = qh;   // level h: k0-7 = s2h
            *(half8*)(tb + 512)  = vh;   //          k8-15 = sh
            *(half8*)(tb + 1024) = qm;   // level m
            *(half8*)(tb + 1536) = vm;
            *(half8*)(tb + 2048) = ql;   // level l
            *(half8*)(tb + 2560) = vl;
        }
        // ---- prefetch next set (latency hides under tile loop) ----
        if (set + 1 < NSETS) {
            int n0 = (set + 1) * SETSZ + tid, n1 = n0 + TPB;
            pf0 = p4[2 * n0]; pf1 = p4[2 * n0 + 1];
            pf2 = p4[2 * n1]; pf3 = p4[2 * n1 + 1];
        }
        __syncthreads();

        #pragma unroll
        for (int t = 0; t < TPS; ++t) {
            const int tb = t * 3072;
            half8 Bh = *(const half8*)(sb + tb + lofs);
            half8 Bm = *(const half8*)(sb + tb + 1024 + lofs);
            half8 Bl = *(const half8*)(sb + tb + 2048 + lofs);
            int n = set * SETSZ + t * 32 + col;
            #pragma unroll
            for (int rb = 0; rb < RB; ++rb) {
                f32x16 acc;
                acc = __builtin_amdgcn_mfma_f32_32x32x16_f16(ah[rb], Bh, z16, 0, 0, 0);
                acc = __builtin_amdgcn_mfma_f32_32x32x16_f16(ah[rb], Bm, acc, 0, 0, 0);
                acc = __builtin_amdgcn_mfma_f32_32x32x16_f16(am[rb], Bh, acc, 0, 0, 0);
                acc = __builtin_amdgcn_mfma_f32_32x32x16_f16(am[rb], Bm, acc, 0, 0, 0);
                acc = __builtin_amdgcn_mfma_f32_32x32x16_f16(ah[rb], Bl, acc, 0, 0, 0);
                acc = __builtin_amdgcn_mfma_f32_32x32x16_f16(al[rb], Bh, acc, 0, 0, 0);
                #pragma unroll
                for (int j = 0; j < 16; ++j) {
                    if (acc[j] > best[rb][j]) { best[rb][j] = acc[j]; bidx[rb][j] = n; }
                }
            }
        }
        __syncthreads();
    }

    // ---- argmax reduce across the 32 columns (tie -> lowest n) ----
    #pragma unroll
    for (int rb = 0; rb < RB; ++rb) {
        #pragma unroll
        for (int j = 0; j < 16; ++j) {
            #pragma unroll
            for (int m = 1; m < 32; m <<= 1) {
                float os = __shfl_xor(best[rb][j], m, 64);
                int oi = __shfl_xor(bidx[rb][j], m, 64);
                if (os > best[rb][j] || (os == best[rb][j] && oi < bidx[rb][j])) {
                    best[rb][j] = os; bidx[rb][j] = oi;
                }
            }
        }
    }

    // ---- epilogue: bounce bidx through LDS to spread rows over 32 lanes ----
    #pragma unroll
    for (int rb = 0; rb < RB; ++rb) {
        if (col == 0) {
            #pragma unroll
            for (int j = 0; j < 16; ++j) ebuf[w][kh][j] = bidx[rb][j];
        }
        // same-wave DS write->read: compiler orders via lgkmcnt
        if (lane < 32) {
            int half_ = (lane >> 4) & 1, j = lane & 15;
            int n = ebuf[w][half_][j];
            int row = (j & 3) + 8 * (j >> 2) + 4 * half_;
            int r = rowbase + rb * 32 + row;
            int b = r >> 14, pos = (r >> 2) & (L - 1), ns = r & 3;
            out[(size_t)BB * C2 * L + ((size_t)b * NG + ns) * L + pos] = (float)n;
            float4 uu = p4[2 * n], vv = p4[2 * n + 1];
            float sv[8] = {uu.x, uu.y, uu.z, uu.w, vv.x, vv.y, vv.z, vv.w};
            #pragma unroll
            for (int g = 0; g < 8; ++g) {
                out[((size_t)b * C2 + g * NG + ns) * L + pos] = sv[g];
            }
        }
    }
}

extern "C" void kernel_launch(void* const* d_in, const int* in_sizes, int n_in,
                              void* d_out, int out_size, void* d_ws, size_t ws_size,
                              hipStream_t stream) {
    const float* z = (const float*)d_in[0];
    const float* prior = (const float*)d_in[1];
    float* out = (float*)d_out;
    dim3 grid((BB * L * NG) / ROWSPB);   // 65536 rows / 128 = 512 blocks
    dim3 block(TPB);
    hipLaunchKernelGGL(gqreg_kernel, grid, block, 0, stream, z, prior, out);
}

// Round 9
// 51.462 us; speedup vs baseline: 1.2708x; 1.2708x over previous
//
#include <hip/hip_runtime.h>
#include <math.h>

#define L 4096
#define C2 32
#define CTOT 64
#define BB 4
#define NG 4
#define NSAMP 2048
#define NSETS 8
#define TPB 256              // 4 waves: rt = w>>1 (row-tile), sh = w&1 (sample-half)
#define ROWSPB 64
#define WS_NEED (64 * 3072)  // 64 tiles x 3 KB presplit B-data

typedef _Float16 half8 __attribute__((ext_vector_type(8)));
typedef float f32x16 __attribute__((ext_vector_type(16)));

__device__ __forceinline__ void split3(float x, _Float16& h, _Float16& m, _Float16& l) {
    h = (_Float16)x; float r1 = x - (float)h;
    m = (_Float16)r1; float r2 = r1 - (float)m;
    l = (_Float16)r2;
}

// ---- kernel 1: split prior samples into 3-level f16 B-layout in ws ----
// tile g = n>>5 (3072 B each): level*1024 + kh*512 + col*16; kh0 = s^2 terms,
// kh1 = s terms; levels h/m/l.
__global__ __launch_bounds__(256) void presplit_kernel(
    const float* __restrict__ prior, char* __restrict__ ws)
{
    int n = blockIdx.x * 256 + threadIdx.x;
    const float4* p4 = (const float4*)prior;
    float4 u = p4[2 * n], v = p4[2 * n + 1];
    float s[8] = {u.x, u.y, u.z, u.w, v.x, v.y, v.z, v.w};
    half8 qh, qm, ql, vh, vm, vl;
    #pragma unroll
    for (int g = 0; g < 8; ++g) {
        _Float16 hh, mm, ll;
        split3(s[g] * s[g], hh, mm, ll);
        qh[g] = hh; qm[g] = mm; ql[g] = ll;
        split3(s[g], hh, mm, ll);
        vh[g] = hh; vm[g] = mm; vl[g] = ll;
    }
    char* tb = ws + (size_t)(n >> 5) * 3072 + (size_t)(n & 31) * 16;
    *(half8*)(tb + 0)    = qh;
    *(half8*)(tb + 512)  = vh;
    *(half8*)(tb + 1024) = qm;
    *(half8*)(tb + 1536) = vm;
    *(half8*)(tb + 2048) = ql;
    *(half8*)(tb + 2560) = vl;
}

// ---- kernel 2: score + argmax on 32x32x16 f16 MFMA (3-way split, 6 terms;
// numerics identical to R7/R8, absmax 0). Wave = (row-tile rt: 32 rows) x
// (sample-half sh: 1024 samples). 4096 waves total = 4/SIMD. Per set stage
// 256 samples (128/half, 24 KB); merge halves via LDS at end (half-0 owns all
// lower n -> strict > merge preserves jnp.argmax tie-break).
__global__ __launch_bounds__(TPB) void gqreg_main(
    const float* __restrict__ z, const float* __restrict__ prior,
    float* __restrict__ out, const char* __restrict__ wsb, int use_ws)
{
    __shared__ char smem[24576];      // staging; reused as merge buffer
    __shared__ int ebuf[2][2][16];    // epilogue bounce [rt][kh][reg]

    const int tid = threadIdx.x;
    const int lane = tid & 63;
    const int w = tid >> 6;
    const int rt = w >> 1;
    const int sh = w & 1;
    const int col = lane & 31;
    const int kh = lane >> 5;
    const float4* p4 = (const float4*)prior;

    // ---- A coefficients: lane holds A[row=col][k=kh*8+g]; k0-7=ca, k8-15=cb ----
    const int rowbase = blockIdx.x * ROWSPB + rt * 32;
    half8 ah, am, al;
    {
        int r = rowbase + col;
        int b = r >> 14, pos = (r >> 2) & (L - 1), ns = r & 3;
        const float* zb = z + (size_t)b * CTOT * L + pos;
        #pragma unroll
        for (int g = 0; g < 8; ++g) {
            float mu = zb[(size_t)(g * NG + ns) * L];
            float lv = zb[(size_t)(C2 + g * NG + ns) * L];
            lv = fminf(fmaxf(lv, -30.f), 20.f);
            float iv = expf(-lv);
            float x = kh ? (mu * iv) : (0.5f - 0.5f * iv);
            _Float16 xh, xm, xl;
            split3(x, xh, xm, xl);
            ah[g] = xh; am[g] = xm; al[g] = xl;
        }
    }

    const int lofs = kh * 512 + col * 16;
    float best[16];
    int bidx[16];
    #pragma unroll
    for (int j = 0; j < 16; ++j) { best[j] = -INFINITY; bidx[j] = 0; }
    const f32x16 z16 = {};

    for (int s = 0; s < NSETS; ++s) {
        if (s > 0) __syncthreads();   // previous set fully consumed

        if (use_ws) {
            // raw copy of presplit data: 1536 16B pieces; half0 -> [0,12K), half1 -> [12K,24K)
            #pragma unroll
            for (int i = 0; i < 6; ++i) {
                int p = tid + i * 256;
                int h2 = (p >= 768) ? 1 : 0;
                const char* src = wsb + (size_t)(h2 * 32 + s * 4) * 3072 + (size_t)(p - h2 * 768) * 16;
                *(float4*)(smem + (size_t)p * 16) = *(const float4*)src;
            }
        } else {
            // fallback: in-kernel split3 staging (R8-validated pattern)
            int h2 = tid >> 7, loc = tid & 127;
            int n = h2 * 1024 + s * 128 + loc;
            float4 u = p4[2 * n], v = p4[2 * n + 1];
            float sv[8] = {u.x, u.y, u.z, u.w, v.x, v.y, v.z, v.w};
            half8 qh, qm, ql, vh, vm, vl;
            #pragma unroll
            for (int g = 0; g < 8; ++g) {
                _Float16 hh, mm, ll;
                split3(sv[g] * sv[g], hh, mm, ll);
                qh[g] = hh; qm[g] = mm; ql[g] = ll;
                split3(sv[g], hh, mm, ll);
                vh[g] = hh; vm[g] = mm; vl[g] = ll;
            }
            char* tb = smem + (size_t)(h2 * 4 + (loc >> 5)) * 3072 + (size_t)(loc & 31) * 16;
            *(half8*)(tb + 0)    = qh;
            *(half8*)(tb + 512)  = vh;
            *(half8*)(tb + 1024) = qm;
            *(half8*)(tb + 1536) = vm;
            *(half8*)(tb + 2048) = ql;
            *(half8*)(tb + 2560) = vl;
        }
        __syncthreads();

        #pragma unroll
        for (int ti = 0; ti < 4; ++ti) {
            const char* tb = smem + (size_t)(sh * 4 + ti) * 3072;
            half8 Bh = *(const half8*)(tb + lofs);
            half8 Bm = *(const half8*)(tb + 1024 + lofs);
            half8 Bl = *(const half8*)(tb + 2048 + lofs);
            int n = sh * 1024 + s * 128 + ti * 32 + col;
            f32x16 acc;
            acc = __builtin_amdgcn_mfma_f32_32x32x16_f16(ah, Bh, z16, 0, 0, 0);
            acc = __builtin_amdgcn_mfma_f32_32x32x16_f16(ah, Bm, acc, 0, 0, 0);
            acc = __builtin_amdgcn_mfma_f32_32x32x16_f16(am, Bh, acc, 0, 0, 0);
            acc = __builtin_amdgcn_mfma_f32_32x32x16_f16(am, Bm, acc, 0, 0, 0);
            acc = __builtin_amdgcn_mfma_f32_32x32x16_f16(ah, Bl, acc, 0, 0, 0);
            acc = __builtin_amdgcn_mfma_f32_32x32x16_f16(al, Bh, acc, 0, 0, 0);
            #pragma unroll
            for (int j = 0; j < 16; ++j) {
                if (acc[j] > best[j]) { best[j] = acc[j]; bidx[j] = n; }
            }
        }
    }

    // ---- merge sample-halves: sh=1 posts to LDS, sh=0 merges (strict >) ----
    __syncthreads();
    float* mb_best = (float*)smem;                 // [2][64][16]
    int* mb_idx = (int*)(smem + 8192);
    if (sh == 1) {
        int base = (rt * 64 + lane) * 16;
        #pragma unroll
        for (int j = 0; j < 16; ++j) { mb_best[base + j] = best[j]; mb_idx[base + j] = bidx[j]; }
    }
    __syncthreads();
    if (sh == 0) {
        int base = (rt * 64 + lane) * 16;
        #pragma unroll
        for (int j = 0; j < 16; ++j) {
            float ob = mb_best[base + j];
            int oi = mb_idx[base + j];
            if (ob > best[j]) { best[j] = ob; bidx[j] = oi; }
        }
        // ---- argmax reduce across 32 columns (within kh half; tie -> lowest n) ----
        #pragma unroll
        for (int j = 0; j < 16; ++j) {
            #pragma unroll
            for (int m = 1; m < 32; m <<= 1) {
                float os = __shfl_xor(best[j], m, 64);
                int oi = __shfl_xor(bidx[j], m, 64);
                if (os > best[j] || (os == best[j] && oi < bidx[j])) {
                    best[j] = os; bidx[j] = oi;
                }
            }
        }
        // ---- epilogue: bounce through LDS to spread 32 rows over lanes ----
        if (col == 0) {
            #pragma unroll
            for (int j = 0; j < 16; ++j) ebuf[rt][kh][j] = bidx[j];
        }
        if (lane < 32) {
            int half_ = (lane >> 4) & 1, j = lane & 15;
            int n = ebuf[rt][half_][j];
            int row = (j & 3) + 8 * (j >> 2) + 4 * half_;
            int r = rowbase + row;
            int b = r >> 14, pos = (r >> 2) & (L - 1), ns = r & 3;
            out[(size_t)BB * C2 * L + ((size_t)b * NG + ns) * L + pos] = (float)n;
            float4 uu = p4[2 * n], vv = p4[2 * n + 1];
            float sv[8] = {uu.x, uu.y, uu.z, uu.w, vv.x, vv.y, vv.z, vv.w};
            #pragma unroll
            for (int g = 0; g < 8; ++g) {
                out[((size_t)b * C2 + g * NG + ns) * L + pos] = sv[g];
            }
        }
    }
}

extern "C" void kernel_launch(void* const* d_in, const int* in_sizes, int n_in,
                              void* d_out, int out_size, void* d_ws, size_t ws_size,
                              hipStream_t stream) {
    const float* z = (const float*)d_in[0];
    const float* prior = (const float*)d_in[1];
    float* out = (float*)d_out;
    char* ws = (char*)d_ws;
    int use_ws = (ws_size >= (size_t)WS_NEED) ? 1 : 0;

    if (use_ws) {
        hipLaunchKernelGGL(presplit_kernel, dim3(NSAMP / 256), dim3(256), 0, stream,
                           prior, ws);
    }
    hipLaunchKernelGGL(gqreg_main, dim3((BB * L * NG) / ROWSPB), dim3(TPB), 0, stream,
                       z, prior, out, (const char*)ws, use_ws);
}

// Round 10
// 50.684 us; speedup vs baseline: 1.2903x; 1.0153x over previous
//
#include <hip/hip_runtime.h>
#include <math.h>

#define L 4096
#define C2 32
#define CTOT 64
#define BB 4
#define NG 4
#define NSAMP 2048
#define TPB 256              // 4 waves: rt = w>>1 (row-tile), sh = w&1 (sample-half)
#define ROWSPB 64
#define WS_NEED (64 * 3072)  // 64 tiles x 3 KB presplit B-data

typedef _Float16 half8 __attribute__((ext_vector_type(8)));
typedef float f32x16 __attribute__((ext_vector_type(16)));

__device__ __forceinline__ void split3(float x, _Float16& h, _Float16& m, _Float16& l) {
    h = (_Float16)x; float r1 = x - (float)h;
    m = (_Float16)r1; float r2 = r1 - (float)m;
    l = (_Float16)r2;
}

// ---- kernel 1: split prior samples into 3-level f16 B-layout in ws ----
// tile = n>>5 (3072 B each): level*1024 + kh*512 + col*16; kh0 = s^2, kh1 = s.
__global__ __launch_bounds__(256) void presplit_kernel(
    const float* __restrict__ prior, char* __restrict__ ws)
{
    int n = blockIdx.x * 256 + threadIdx.x;
    const float4* p4 = (const float4*)prior;
    float4 u = p4[2 * n], v = p4[2 * n + 1];
    float s[8] = {u.x, u.y, u.z, u.w, v.x, v.y, v.z, v.w};
    half8 qh, qm, ql, vh, vm, vl;
    #pragma unroll
    for (int g = 0; g < 8; ++g) {
        _Float16 hh, mm, ll;
        split3(s[g] * s[g], hh, mm, ll);
        qh[g] = hh; qm[g] = mm; ql[g] = ll;
        split3(s[g], hh, mm, ll);
        vh[g] = hh; vm[g] = mm; vl[g] = ll;
    }
    char* tb = ws + (size_t)(n >> 5) * 3072 + (size_t)(n & 31) * 16;
    *(half8*)(tb + 0)    = qh;
    *(half8*)(tb + 512)  = vh;
    *(half8*)(tb + 1024) = qm;
    *(half8*)(tb + 1536) = vm;
    *(half8*)(tb + 2048) = ql;
    *(half8*)(tb + 2560) = vl;
}

// ---- kernel 2: 32x32x16 f16 MFMA score+argmax (3-way split, 6 terms —
// numerics identical to R7..R9, absmax 0). Wave = (rt: 32 rows) x (sh: 1024
// samples = 32 tiles). 4096 waves = 4/SIMD. B fragments read DIRECTLY from
// global ws (192 KB, L1/L2-resident): no LDS staging, no main-loop barriers.
// A-frag: lane holds A[row=col][k=kh*8+g], k0-7 = ca, k8-15 = cb.
// D: col=lane&31, row=(reg&3)+8*(reg>>2)+4*(lane>>5) (m101, HW-validated R8/R9).
__global__ __launch_bounds__(TPB) void gqreg_main(
    const float* __restrict__ z, const float* __restrict__ prior,
    float* __restrict__ out, const char* __restrict__ wsb, int use_ws)
{
    __shared__ float mbB[2][2][2][16];   // [rt][sh][kh][j]
    __shared__ int   mbI[2][2][2][16];

    const int tid = threadIdx.x;
    const int lane = tid & 63;
    const int w = tid >> 6;
    const int rt = w >> 1;
    const int sh = w & 1;
    const int col = lane & 31;
    const int kh = lane >> 5;
    const float4* p4 = (const float4*)prior;

    // ---- A coefficients ----
    const int rowbase = blockIdx.x * ROWSPB + rt * 32;
    half8 ah, am, al;
    {
        int r = rowbase + col;
        int b = r >> 14, pos = (r >> 2) & (L - 1), ns = r & 3;
        const float* zb = z + (size_t)b * CTOT * L + pos;
        #pragma unroll
        for (int g = 0; g < 8; ++g) {
            float mu = zb[(size_t)(g * NG + ns) * L];
            float lv = zb[(size_t)(C2 + g * NG + ns) * L];
            lv = fminf(fmaxf(lv, -30.f), 20.f);
            float iv = expf(-lv);
            float x = kh ? (mu * iv) : (0.5f - 0.5f * iv);
            _Float16 xh, xm, xl;
            split3(x, xh, xm, xl);
            ah[g] = xh; am[g] = xm; al[g] = xl;
        }
    }

    float best[16];
    int bidx[16];
    #pragma unroll
    for (int j = 0; j < 16; ++j) { best[j] = -INFINITY; bidx[j] = 0; }
    const f32x16 z16 = {};
    const char* wbase = wsb + (size_t)(sh * 32) * 3072 + (size_t)(kh * 512 + col * 16);

    if (use_ws) {
        #pragma unroll 2
        for (int t = 0; t < 32; ++t) {
            const char* tb = wbase + (size_t)t * 3072;
            half8 Bh = *(const half8*)(tb + 0);
            half8 Bm = *(const half8*)(tb + 1024);
            half8 Bl = *(const half8*)(tb + 2048);
            int n = (sh * 32 + t) * 32 + col;
            f32x16 acc;
            acc = __builtin_amdgcn_mfma_f32_32x32x16_f16(ah, Bh, z16, 0, 0, 0);
            acc = __builtin_amdgcn_mfma_f32_32x32x16_f16(ah, Bm, acc, 0, 0, 0);
            acc = __builtin_amdgcn_mfma_f32_32x32x16_f16(am, Bh, acc, 0, 0, 0);
            acc = __builtin_amdgcn_mfma_f32_32x32x16_f16(am, Bm, acc, 0, 0, 0);
            acc = __builtin_amdgcn_mfma_f32_32x32x16_f16(ah, Bl, acc, 0, 0, 0);
            acc = __builtin_amdgcn_mfma_f32_32x32x16_f16(al, Bh, acc, 0, 0, 0);
            #pragma unroll
            for (int j = 0; j < 16; ++j) {
                if (acc[j] > best[j]) { best[j] = acc[j]; bidx[j] = n; }
            }
        }
    } else {
        // fallback: split B in-VALU per tile (no ws needed)
        #pragma unroll 2
        for (int t = 0; t < 32; ++t) {
            int n = (sh * 32 + t) * 32 + col;
            float4 u = p4[2 * n], v = p4[2 * n + 1];
            float sv[8] = {u.x, u.y, u.z, u.w, v.x, v.y, v.z, v.w};
            half8 Bh, Bm, Bl;
            #pragma unroll
            for (int g = 0; g < 8; ++g) {
                float x = kh ? sv[g] : sv[g] * sv[g];
                _Float16 hh, mm, ll;
                split3(x, hh, mm, ll);
                Bh[g] = hh; Bm[g] = mm; Bl[g] = ll;
            }
            f32x16 acc;
            acc = __builtin_amdgcn_mfma_f32_32x32x16_f16(ah, Bh, z16, 0, 0, 0);
            acc = __builtin_amdgcn_mfma_f32_32x32x16_f16(ah, Bm, acc, 0, 0, 0);
            acc = __builtin_amdgcn_mfma_f32_32x32x16_f16(am, Bh, acc, 0, 0, 0);
            acc = __builtin_amdgcn_mfma_f32_32x32x16_f16(am, Bm, acc, 0, 0, 0);
            acc = __builtin_amdgcn_mfma_f32_32x32x16_f16(ah, Bl, acc, 0, 0, 0);
            acc = __builtin_amdgcn_mfma_f32_32x32x16_f16(al, Bh, acc, 0, 0, 0);
            #pragma unroll
            for (int j = 0; j < 16; ++j) {
                if (acc[j] > best[j]) { best[j] = acc[j]; bidx[j] = n; }
            }
        }
    }

    // ---- cross-col reduce within kh half (tie -> lowest n) ----
    #pragma unroll
    for (int j = 0; j < 16; ++j) {
        #pragma unroll
        for (int m = 1; m < 32; m <<= 1) {
            float os = __shfl_xor(best[j], m, 64);
            int oi = __shfl_xor(bidx[j], m, 64);
            if (os > best[j] || (os == best[j] && oi < bidx[j])) {
                best[j] = os; bidx[j] = oi;
            }
        }
    }

    // ---- post reduced values (2 active lanes per wave -> no conflicts) ----
    if (col == 0) {
        #pragma unroll
        for (int j = 0; j < 16; ++j) {
            mbB[rt][sh][kh][j] = best[j];
            mbI[rt][sh][kh][j] = bidx[j];
        }
    }
    __syncthreads();

    // ---- wave 0 merges sample-halves (sh0 n < sh1 n: strict > keeps lowest)
    //      and writes all 64 output rows, one per lane ----
    if (w == 0) {
        int rt_o = lane >> 5;
        int rr = lane & 31;
        int kh_o = (rr >> 2) & 1;
        int j_o = (rr & 3) | ((rr >> 3) << 2);
        float b0 = mbB[rt_o][0][kh_o][j_o];
        int i0 = mbI[rt_o][0][kh_o][j_o];
        float b1 = mbB[rt_o][1][kh_o][j_o];
        int i1 = mbI[rt_o][1][kh_o][j_o];
        int n = (b1 > b0) ? i1 : i0;
        int r = blockIdx.x * ROWSPB + rt_o * 32 + rr;
        int b = r >> 14, pos = (r >> 2) & (L - 1), ns = r & 3;
        out[(size_t)BB * C2 * L + ((size_t)b * NG + ns) * L + pos] = (float)n;
        float4 uu = p4[2 * n], vv = p4[2 * n + 1];
        float sv[8] = {uu.x, uu.y, uu.z, uu.w, vv.x, vv.y, vv.z, vv.w};
        #pragma unroll
        for (int g = 0; g < 8; ++g) {
            out[((size_t)b * C2 + g * NG + ns) * L + pos] = sv[g];
        }
    }
}

extern "C" void kernel_launch(void* const* d_in, const int* in_sizes, int n_in,
                              void* d_out, int out_size, void* d_ws, size_t ws_size,
                              hipStream_t stream) {
    const float* z = (const float*)d_in[0];
    const float* prior = (const float*)d_in[1];
    float* out = (float*)d_out;
    char* ws = (char*)d_ws;
    int use_ws = (ws_size >= (size_t)WS_NEED) ? 1 : 0;

    if (use_ws) {
        hipLaunchKernelGGL(presplit_kernel, dim3(NSAMP / 256), dim3(256), 0, stream,
                           prior, ws);
    }
    hipLaunchKernelGGL(gqreg_main, dim3((BB * L * NG) / ROWSPB), dim3(TPB), 0, stream,
                       z, prior, out, (const char*)ws, use_ws);
}